// Round 16
// baseline (105.745 us; speedup 1.0000x reference)
//
#include <hip/hip_runtime.h>
#include <hip/hip_bf16.h>
#include <stdint.h>

// DenseConv2d: input (32,128,56,56) f32, weight (256,128,3,3) f32, bias (256) f32
// stride 1, pad 1 -> out (32,256,56,56) f32.
// Round 16: A-direct hybrid. A-fragments load global->reg (w3 is L1/L2-hot,
// only 8 frags in flight, named even/odd banks, 1-tile prefetch covered by the
// top-of-tile counted vmcnt). B stays LDS-staged (3 rotating 16KB buffers,
// stage distance 2, ONE barrier/tile). Halves LDS reads AND writes per tile.

typedef __attribute__((ext_vector_type(8))) short bf16x8;
typedef __attribute__((ext_vector_type(8))) unsigned short ushort8;
typedef __attribute__((ext_vector_type(4))) float f32x4;

#define HW       56
#define SPATIAL  3136
#define C_IN     128
#define K_OUT    256
#define GEMM_K   1152
#define GEMM_N   100352      // 32*3136

#define PHW      58
#define PIMG     3364        // 58*58
#define PADTOT_AL 107656     // 32*3364 + 8 slack positions

#define NTILE    18          // K-tiles of 64 (tap = t>>1, ch-half = t&1)
#define BBUF     8192        // halves per B buffer (16 KiB)

__device__ __forceinline__ unsigned short f2bf(float f) {
    union { float f; unsigned int u; } v; v.f = f;
    unsigned int u = v.u + 0x7FFFu + ((v.u >> 16) & 1u);   // RTNE
    return (unsigned short)(u >> 16);
}

__device__ __forceinline__ void gload16(const unsigned short* g, unsigned short* l) {
    __builtin_amdgcn_global_load_lds(
        (const __attribute__((address_space(1))) unsigned int*)(g),
        (__attribute__((address_space(3))) unsigned int*)(l),
        16, 0, 0);
}

// fused prepass: blocks 0..1151 -> weight transform; 1152..1265 -> border zero.
// w3 chunk (rc,tap,cc) = 512 halves; slot s = l*8+j holds
// W[row rc*16 + (l&15)][ch cc*32 + (l>>4)*8 + j][tap]  (one wave A-fragment).
__global__ __launch_bounds__(256)
void prep_kernel(const float* __restrict__ w, unsigned short* __restrict__ w3,
                 unsigned short* __restrict__ pad) {
    if (blockIdx.x < 1152) {
        int idx = blockIdx.x * 256 + threadIdx.x;    // 294912
        int rc   = idx / 18432;
        int rem  = idx % 18432;
        int tap  = rem / 2048;
        int rem2 = rem % 2048;
        int cc   = rem2 / 512;
        int s    = rem2 % 512;
        int l    = s >> 3, j = s & 7;
        int ko   = rc * 16 + (l & 15);
        int c    = cc * 32 + ((l >> 4) << 3) + j;
        w3[idx] = f2bf(w[(ko * C_IN + c) * 9 + tap]);
    } else {
        int idx = (blockIdx.x - 1152) * 256 + threadIdx.x;   // 4*32*228 = 29184
        if (idx >= 29184) return;
        int cc  = idx / 7296;
        int r   = idx % 7296;
        int img = r / 228;
        int p   = r % 228;
        int pos;
        if (p < 58)       pos = p;
        else if (p < 116) pos = 57 * PHW + (p - 58);
        else { int i = p - 116; pos = (1 + (i >> 1)) * PHW + (i & 1) * 57; }
        unsigned short* d = pad + (size_t)cc * PADTOT_AL * 32
                          + ((size_t)img * PIMG + pos) * 32;
        const ushort8 z = (ushort8){0,0,0,0,0,0,0,0};
        *reinterpret_cast<ushort8*>(d)      = z;
        *reinterpret_cast<ushort8*>(d + 8)  = z;
        *reinterpret_cast<ushort8*>(d + 16) = z;
        *reinterpret_cast<ushort8*>(d + 24) = z;
    }
}

// input [32][128][56][56] f32 -> pad[4cc][32img][58*58][32ch] bf16 (interior)
__global__ __launch_bounds__(256)
void intrans_kernel(const float* __restrict__ in, unsigned short* __restrict__ pad) {
    __shared__ __attribute__((aligned(16))) unsigned short l[56 * 136];
    const int bx = blockIdx.x;                   // 32*56
    const int n = bx / HW, h = bx % HW;
    const int tid = threadIdx.x;
    const float* src = in + (size_t)n * C_IN * SPATIAL + h * HW;
    #pragma unroll
    for (int i = 0; i < 28; ++i) {               // 7168 = 28*256
        int idx = i * 256 + tid;
        int c = idx / HW, w = idx % HW;
        l[w * 136 + c] = f2bf(src[(size_t)c * SPATIAL + w]);
    }
    __syncthreads();
    const int prow = n * PIMG + (h + 1) * PHW;
    #pragma unroll
    for (int j = 0; j < 4; ++j) {
        int chunk = j * 256 + tid;               // 896 = 56*16 chunks of 8 halves
        if (chunk < 896) {
            int w = chunk >> 4, c8 = chunk & 15;
            int cc = c8 >> 2, sub = c8 & 3;
            unsigned short* dst = pad + (size_t)cc * PADTOT_AL * 32
                                + (size_t)(prow + w + 1) * 32 + sub * 8;
            *reinterpret_cast<ushort8*>(dst) =
                *reinterpret_cast<const ushort8*>(&l[w * 136 + c8 * 8]);
        }
    }
}

// ---------------- main kernel: A-direct hybrid ----------------
// B LDS: 3 buffers x 8192 halves; buffer = chunks [(bc*2+kc)*512] bc=0..7.
// Chunk slot l = (col l&15, k-gran l>>4).
__global__ __launch_bounds__(256, 2)
void conv_hyb(const unsigned short* __restrict__ pad,   // [4][PADTOT_AL][32]
              const unsigned short* __restrict__ w3,    // chunked weights
              const float* __restrict__ bias,
              float* __restrict__ out) {
    __shared__ __attribute__((aligned(16))) unsigned short lds[3 * BBUF]; // 48 KiB

    const int tid  = threadIdx.x;
    const int wave = tid >> 6;          // 0..3
    const int lane = tid & 63;
    const int la   = lane & 15;
    const int lkh  = lane >> 4;

    // bijective XCD swizzle: 1568 blocks = 8 * 196; m-pairs adjacent for L2 B reuse
    const int bid = blockIdx.x;
    const int swz = (bid & 7) * 196 + (bid >> 3);
    const int mt  = swz & 1, nt = swz >> 1;       // nt 0..783
    const int m0  = mt * 128;
    const int g0  = nt * 128;

    const int wr = wave >> 1, wc = wave & 1;      // 2x2 waves, 64x64 tiles

    // A fragment sources (global, L1/L2-hot; same addr for both waves per wr)
    const unsigned short* asrc[4];
    #pragma unroll
    for (int mi = 0; mi < 4; ++mi)
        asrc[mi] = w3 + (size_t)(mt * 8 + wr * 4 + mi) * 18432 + lane * 8;

    // B staging sources: wave stages col-chunks 2w, 2w+1
    const unsigned short* bsrc0;
    const unsigned short* bsrc1;
    {
        int col = g0 + (wave * 2 + 0) * 16 + la;
        int img = col / SPATIAL;
        int pos = col - img * SPATIAL;
        int oh  = pos / HW, ow = pos - oh * HW;
        bsrc0 = pad + (size_t)(img * PIMG + (oh + 1) * PHW + (ow + 1)) * 32 + lkh * 8;
        col = g0 + (wave * 2 + 1) * 16 + la;
        img = col / SPATIAL;
        pos = col - img * SPATIAL;
        oh  = pos / HW; ow = pos - oh * HW;
        bsrc1 = pad + (size_t)(img * PIMG + (oh + 1) * PHW + (ow + 1)) * 32 + lkh * 8;
    }

    f32x4 acc[4][4];
    #pragma unroll
    for (int i = 0; i < 4; ++i)
        #pragma unroll
        for (int j = 0; j < 4; ++j)
            acc[i][j] = (f32x4){0.f, 0.f, 0.f, 0.f};

    // stage BOTH halves of tile tn's B into buf[tn%3]: 4 gloads per wave
    auto STAGEB = [&](int tn) {
        const int tap = tn >> 1;
        const int dr = tap / 3 - 1, dsx = tap % 3 - 1;
        unsigned short* dst = &lds[(tn % 3) * BBUF];
        #pragma unroll
        for (int kc = 0; kc < 2; ++kc) {
            const int cc = (tn & 1) * 2 + kc;
            const ptrdiff_t bofs = (ptrdiff_t)cc * (PADTOT_AL * 32)
                                 + (dr * PHW + dsx) * 32;
            gload16(bsrc0 + bofs, dst + (((wave * 2 + 0) * 2) + kc) * 512);
            gload16(bsrc1 + bofs, dst + (((wave * 2 + 1) * 2) + kc) * 512);
        }
    };

    // A banks: 8 frags each (4 mi x 2 ks), named (rule #20)
    bf16x8 aE[8], aO[8], bv0[4], bv1[4];

#define LOADA(tn, A_) do {                                                   \
    const int tap_ = (tn) >> 1;                                              \
    _Pragma("unroll")                                                        \
    for (int ks = 0; ks < 2; ++ks) {                                         \
        const int cc_ = ((tn) & 1) * 2 + ks;                                 \
        const ptrdiff_t ao_ = (ptrdiff_t)(tap_ * 4 + cc_) * 512;             \
        _Pragma("unroll")                                                    \
        for (int mi = 0; mi < 4; ++mi)                                       \
            A_[mi * 2 + ks] = *reinterpret_cast<const bf16x8*>(asrc[mi] + ao_); \
    }                                                                        \
} while (0)

    // prologue: A(0) first, then B0, B1, B2 (issue order matters for vmcnt)
    LOADA(0, aE);
    STAGEB(0); STAGEB(1); STAGEB(2);

    #pragma unroll
    for (int t = 0; t < NTILE; ++t) {
        // top-of-tile wait: A(t) and B(t) landed; newer stages stay in flight
        if (t == 0)                asm volatile("s_waitcnt vmcnt(8)" ::: "memory");
        else if (t <= NTILE - 3)   asm volatile("s_waitcnt vmcnt(4)" ::: "memory");
        else                       asm volatile("s_waitcnt vmcnt(0)" ::: "memory");
        __builtin_amdgcn_s_barrier();

        // ds_read this tile's 8 B-frags from buf[t%3]
        const unsigned short* Bb = &lds[(t % 3) * BBUF];
        #pragma unroll
        for (int nj = 0; nj < 4; ++nj)
            bv0[nj] = *reinterpret_cast<const bf16x8*>(
                &Bb[((wc * 4 + nj) * 2 + 0) * 512 + lane * 8]);
        #pragma unroll
        for (int nj = 0; nj < 4; ++nj)
            bv1[nj] = *reinterpret_cast<const bf16x8*>(
                &Bb[((wc * 4 + nj) * 2 + 1) * 512 + lane * 8]);

        // issue next loads: A(t+1) -> other bank; B(t+2) -> buf[(t+2)%3]
        if ((t & 1) == 0) { if (t + 1 < NTILE) LOADA(t + 1, aO); }
        else              { if (t + 1 < NTILE) LOADA(t + 1, aE); }
        if (t + 2 < NTILE) STAGEB(t + 2);

        // compute: ks0 cluster while bv1 reads fly, then ks1
        asm volatile("s_waitcnt lgkmcnt(4)" ::: "memory");
        __builtin_amdgcn_sched_barrier(0);
        __builtin_amdgcn_s_setprio(1);
        if ((t & 1) == 0) {
            #pragma unroll
            for (int mi = 0; mi < 4; ++mi)
                #pragma unroll
                for (int nj = 0; nj < 4; ++nj)
                    acc[mi][nj] = __builtin_amdgcn_mfma_f32_16x16x32_bf16(
                        aE[mi * 2 + 0], bv0[nj], acc[mi][nj], 0, 0, 0);
            asm volatile("s_waitcnt lgkmcnt(0)" ::: "memory");
            __builtin_amdgcn_sched_barrier(0);
            #pragma unroll
            for (int mi = 0; mi < 4; ++mi)
                #pragma unroll
                for (int nj = 0; nj < 4; ++nj)
                    acc[mi][nj] = __builtin_amdgcn_mfma_f32_16x16x32_bf16(
                        aE[mi * 2 + 1], bv1[nj], acc[mi][nj], 0, 0, 0);
        } else {
            #pragma unroll
            for (int mi = 0; mi < 4; ++mi)
                #pragma unroll
                for (int nj = 0; nj < 4; ++nj)
                    acc[mi][nj] = __builtin_amdgcn_mfma_f32_16x16x32_bf16(
                        aO[mi * 2 + 0], bv0[nj], acc[mi][nj], 0, 0, 0);
            asm volatile("s_waitcnt lgkmcnt(0)" ::: "memory");
            __builtin_amdgcn_sched_barrier(0);
            #pragma unroll
            for (int mi = 0; mi < 4; ++mi)
                #pragma unroll
                for (int nj = 0; nj < 4; ++nj)
                    acc[mi][nj] = __builtin_amdgcn_mfma_f32_16x16x32_bf16(
                        aO[mi * 2 + 1], bv1[nj], acc[mi][nj], 0, 0, 0);
        }
        __builtin_amdgcn_s_setprio(0);
        // NOTE: each wave's ds_reads of buf[t%3] are drained (lgkmcnt(0))
        // before it reaches tile t+1's barrier, after which buf[t%3] is
        // re-staged (as B(t+3)) -- race-free with ONE barrier per tile.
    }

    // ---- epilogue: D col = lane&15, row = (lane>>4)*4 + reg ----
    #pragma unroll
    for (int mi = 0; mi < 4; ++mi) {
        const int mb = m0 + wr * 64 + mi * 16 + lkh * 4;
        const f32x4 bv4 = *reinterpret_cast<const f32x4*>(&bias[mb]);
        #pragma unroll
        for (int nj = 0; nj < 4; ++nj) {
            const int gcol = g0 + wc * 64 + nj * 16;   // 16-aligned: one image
            const int n2 = gcol / SPATIAL;
            const int p2 = gcol - n2 * SPATIAL + la;
            float* op = out + ((size_t)(n2 * K_OUT + mb)) * SPATIAL + p2;
            op[0]                   = acc[mi][nj][0] + bv4[0];
            op[SPATIAL]             = acc[mi][nj][1] + bv4[1];
            op[2 * SPATIAL]         = acc[mi][nj][2] + bv4[2];
            op[3 * (size_t)SPATIAL] = acc[mi][nj][3] + bv4[3];
        }
    }
#undef LOADA
}

// ---------------- fallback (round-1 path) if ws is too small ----------------
#define LDK 40
__global__ __launch_bounds__(256)
void conv_mfma_fallback(const float* __restrict__ in,
                        const float* __restrict__ wraw,
                        const float* __restrict__ bias,
                        float* __restrict__ out) {
    __shared__ __attribute__((aligned(16))) unsigned short lA[128 * LDK];
    __shared__ __attribute__((aligned(16))) unsigned short lB[128 * LDK];
    const int tid = threadIdx.x;
    const int m0  = blockIdx.y * 128;
    const int g0  = blockIdx.x * 128;
    const int wave = tid >> 6, lane = tid & 63;
    const int wr = wave >> 1, wc = wave & 1;
    const int la = lane & 15, lkh = lane >> 4, lk = lkh * 8;

    f32x4 acc[4][4];
    #pragma unroll
    for (int i = 0; i < 4; ++i)
        #pragma unroll
        for (int j = 0; j < 4; ++j)
            acc[i][j] = (f32x4){0.f, 0.f, 0.f, 0.f};

    const int jj = tid & 127;
    const int kb = (tid >> 7) * 16;
    const int g = g0 + jj;
    const int nimg = g / SPATIAL;
    const int pos  = g % SPATIAL;
    const int oh = pos / HW, ow = pos % HW;

    for (int tap = 0; tap < 9; ++tap) {
        const int dr = tap / 3 - 1, dsx = tap % 3 - 1;
        const int ih = oh + dr, iw = ow + dsx;
        const bool valid = ((unsigned)ih < HW) && ((unsigned)iw < HW);
        const float* src = in + ((nimg * C_IN) * HW + ih) * HW + iw;
        for (int c0 = 0; c0 < C_IN; c0 += 32) {
            #pragma unroll
            for (int i = 0; i < 2; ++i) {
                const int ch = tid * 2 + i;
                const int row = ch >> 2;
                const int kp = (ch & 3) * 8;
                ushort8 v;
                #pragma unroll
                for (int e = 0; e < 8; ++e)
                    v[e] = f2bf(wraw[((m0 + row) * C_IN + c0 + kp + e) * 9 + tap]);
                *reinterpret_cast<ushort8*>(&lA[row * LDK + kp]) = v;
            }
            {
                ushort8 v0, v1;
                #pragma unroll
                for (int i = 0; i < 8; ++i)
                    v0[i] = f2bf(valid ? src[(c0 + kb + i) * SPATIAL] : 0.f);
                #pragma unroll
                for (int i = 0; i < 8; ++i)
                    v1[i] = f2bf(valid ? src[(c0 + kb + 8 + i) * SPATIAL] : 0.f);
                *reinterpret_cast<ushort8*>(&lB[jj * LDK + kb])     = v0;
                *reinterpret_cast<ushort8*>(&lB[jj * LDK + kb + 8]) = v1;
            }
            __syncthreads();
            bf16x8 af[4], bv[4];
            #pragma unroll
            for (int f = 0; f < 4; ++f) {
                af[f] = *reinterpret_cast<const bf16x8*>(&lA[(wr * 64 + f * 16 + la) * LDK + lk]);
                bv[f] = *reinterpret_cast<const bf16x8*>(&lB[(wc * 64 + f * 16 + la) * LDK + lk]);
            }
            #pragma unroll
            for (int fi = 0; fi < 4; ++fi)
                #pragma unroll
                for (int fj = 0; fj < 4; ++fj)
                    acc[fi][fj] = __builtin_amdgcn_mfma_f32_16x16x32_bf16(
                        af[fi], bv[fj], acc[fi][fj], 0, 0, 0);
            __syncthreads();
        }
    }
    const int mbase = m0 + wr * 64;
    const int cbase = g0 + wc * 64;
    #pragma unroll
    for (int fi = 0; fi < 4; ++fi) {
        float bvv[4];
        #pragma unroll
        for (int r = 0; r < 4; ++r)
            bvv[r] = bias[mbase + fi * 16 + lkh * 4 + r];
        #pragma unroll
        for (int fj = 0; fj < 4; ++fj) {
            const int gcol = cbase + fj * 16 + la;
            const int n2 = gcol / SPATIAL;
            const int p2 = gcol % SPATIAL;
            float* op = out + (size_t)(n2 * K_OUT) * SPATIAL + p2;
            #pragma unroll
            for (int r = 0; r < 4; ++r)
                op[(size_t)(mbase + fi * 16 + lkh * 4 + r) * SPATIAL] = acc[fi][fj][r] + bvv[r];
        }
    }
}

extern "C" void kernel_launch(void* const* d_in, const int* in_sizes, int n_in,
                              void* d_out, int out_size, void* d_ws, size_t ws_size,
                              hipStream_t stream) {
    const float* in   = (const float*)d_in[0];
    const float* w    = (const float*)d_in[1];
    const float* bias = (const float*)d_in[2];
    float* out = (float*)d_out;

    // ws layout (halves): pad [4*PADTOT_AL*32] | w3 [294912]
    const size_t pad_halves = 4ull * PADTOT_AL * 32ull;     // 13,779,968
    const size_t need_bytes = (pad_halves + 294912ull) * 2ull;  // ~28.15 MB

    if (ws_size >= need_bytes) {
        unsigned short* pad = (unsigned short*)d_ws;
        unsigned short* w3  = pad + pad_halves;
        prep_kernel<<<1152 + 114, 256, 0, stream>>>(w, w3, pad);
        intrans_kernel<<<32 * HW, 256, 0, stream>>>(in, pad);
        conv_hyb<<<(GEMM_N / 128) * (K_OUT / 128), 256, 0, stream>>>(pad, w3, bias, out);
    } else {
        dim3 grid(GEMM_N / 128, K_OUT / 128);
        conv_mfma_fallback<<<grid, 256, 0, stream>>>(in, w, bias, out);
    }
}